// Round 8
// baseline (125.921 us; speedup 1.0000x reference)
//
#include <hip/hip_runtime.h>
#include <cstdint>

#define T_TOK 4096
#define KDIM 2048
#define NE 64
#define NP 2
#define EE 32
#define CAP 160
#define COMB_ELEMS 41943040ull /* 8192 * 5120 */
#define OUT_ELEMS 83886081ull  /* 1 + 2*COMB */
#define SMALLF 65536           /* floats of small scratch */
#define NFB 4096               /* fill blocks */
#define NGB 128                /* gemm blocks */
#define TOT4 20971520          /* float4s covering OUT_ELEMS-1 */

// ---- fused: blocks 0..127 = GEMM(32r x 64e x 2048k)+softmax, rest = fill ----
__global__ __launch_bounds__(256) void k_fused(const float* __restrict__ x,
                                               const float* __restrict__ W,
                                               float2* __restrict__ g12,
                                               int* __restrict__ idxs,
                                               float* __restrict__ me_part,
                                               float* __restrict__ out,
                                               int s2lo, int s2hi, int fillLast) {
  __shared__ float xs[32][36];  // 16B-aligned rows, staggered banks
  __shared__ float wt[32][68];  // [k][e]; reused as gates lg[32 tok][64+pad]
  const int tid = threadIdx.x;
  if (blockIdx.x >= NGB) {      // ---------- fill role ----------
    const int fb = blockIdx.x - NGB;
    float4* p4 = reinterpret_cast<float4*>(out);
    const float4 z4 = make_float4(0.f, 0.f, 0.f, 0.f);
    const int start = fb * 5120;
#pragma unroll
    for (int j = 0; j < 20; ++j) {
      const int i4 = start + tid + j * 256;
      if (i4 >= s2lo && i4 < s2hi) continue;  // scratch window (aliasing path)
      p4[i4] = z4;
    }
    if (fillLast && fb == NFB - 1 && tid == 255) out[OUT_ELEMS - 1] = 0.f;
    return;
  }
  // ---------- gemm role ----------
  const int r0 = blockIdx.x * 32;
  const int er = tid & 15;       // experts er*4..+3
  const int rg = tid >> 4;       // rows rg*2, rg*2+1
  const int lrow = tid >> 3, lkq = (tid & 7) * 4;  // staging coords
  float tot[2][4], chunk[2][4];
#pragma unroll
  for (int i = 0; i < 2; ++i)
#pragma unroll
    for (int c = 0; c < 4; ++c) chunk[i][c] = 0.f;

  float4 sx, sw0, sw1;
  {  // prefetch k-subtile 0
    sx = *reinterpret_cast<const float4*>(&x[(size_t)(r0 + lrow) * KDIM + lkq]);
    sw0 = *reinterpret_cast<const float4*>(&W[(size_t)lrow * KDIM + lkq]);
    sw1 = *reinterpret_cast<const float4*>(&W[(size_t)(lrow + 32) * KDIM + lkq]);
  }
  for (int it = 0; it < 64; ++it) {  // 64 subtiles of 32k (kc = it>>3 chunks)
    __syncthreads();
    *reinterpret_cast<float4*>(&xs[lrow][lkq]) = sx;
    wt[lkq][lrow] = sw0.x; wt[lkq + 1][lrow] = sw0.y;
    wt[lkq + 2][lrow] = sw0.z; wt[lkq + 3][lrow] = sw0.w;
    wt[lkq][lrow + 32] = sw1.x; wt[lkq + 1][lrow + 32] = sw1.y;
    wt[lkq + 2][lrow + 32] = sw1.z; wt[lkq + 3][lrow + 32] = sw1.w;
    if (it < 63) {  // prefetch next subtile under compute
      const int kb = (it + 1) * 32;
      sx = *reinterpret_cast<const float4*>(&x[(size_t)(r0 + lrow) * KDIM + kb + lkq]);
      sw0 = *reinterpret_cast<const float4*>(&W[(size_t)lrow * KDIM + kb + lkq]);
      sw1 = *reinterpret_cast<const float4*>(&W[(size_t)(lrow + 32) * KDIM + kb + lkq]);
    }
    __syncthreads();
#pragma unroll
    for (int k4 = 0; k4 < 8; ++k4) {
      float4 wb[4];
#pragma unroll
      for (int j = 0; j < 4; ++j)
        wb[j] = *reinterpret_cast<const float4*>(&wt[k4 * 4 + j][er * 4]);
#pragma unroll
      for (int i = 0; i < 2; ++i) {
        const float4 xv = *reinterpret_cast<const float4*>(&xs[rg * 2 + i][k4 * 4]);
        // k-ascending nested fmaf: identical within-chunk order to R5-R7
        chunk[i][0] = fmaf(xv.w, wb[3].x, fmaf(xv.z, wb[2].x, fmaf(xv.y, wb[1].x, fmaf(xv.x, wb[0].x, chunk[i][0]))));
        chunk[i][1] = fmaf(xv.w, wb[3].y, fmaf(xv.z, wb[2].y, fmaf(xv.y, wb[1].y, fmaf(xv.x, wb[0].y, chunk[i][1]))));
        chunk[i][2] = fmaf(xv.w, wb[3].z, fmaf(xv.z, wb[2].z, fmaf(xv.y, wb[1].z, fmaf(xv.x, wb[0].z, chunk[i][2]))));
        chunk[i][3] = fmaf(xv.w, wb[3].w, fmaf(xv.z, wb[2].w, fmaf(xv.y, wb[1].w, fmaf(xv.x, wb[0].w, chunk[i][3]))));
      }
    }
    if ((it & 7) == 7) {  // chunk boundary: fold like k_soft's v=p0; v+=p1..p7
#pragma unroll
      for (int i = 0; i < 2; ++i)
#pragma unroll
        for (int c = 0; c < 4; ++c) {
          if (it == 7) tot[i][c] = chunk[i][c];
          else tot[i][c] += chunk[i][c];
          chunk[i][c] = 0.f;
        }
    }
  }
  // ---------- in-block softmax + top2 + me partials (wt reused as lg) -------
  __syncthreads();
#pragma unroll
  for (int i = 0; i < 2; ++i) {
    float4 v; v.x = tot[i][0]; v.y = tot[i][1]; v.z = tot[i][2]; v.w = tot[i][3];
    *reinterpret_cast<float4*>(&wt[rg * 2 + i][er * 4]) = v;
  }
  __syncthreads();
  if (tid < 64) {  // one thread per (token-row, p); ops verbatim from k_soft
    const int row = tid >> 1, p = tid & 1;
    float v[32];
#pragma unroll
    for (int e = 0; e < 32; e += 4) {
      const float4 s = *reinterpret_cast<const float4*>(&wt[row][p * 32 + e]);
      v[e] = s.x; v[e + 1] = s.y; v[e + 2] = s.z; v[e + 3] = s.w;
    }
    float m = v[0];
#pragma unroll
    for (int e = 1; e < 32; ++e) m = fmaxf(m, v[e]);
    float sum = 0.f;
#pragma unroll
    for (int e = 0; e < 32; ++e) { v[e] = expf(v[e] - m); sum += v[e]; }
    const float inv = 1.0f / sum;
#pragma unroll
    for (int e = 0; e < 32; ++e) v[e] *= inv;
    float g1 = -1.f; int i1 = 0;
#pragma unroll
    for (int e = 0; e < 32; ++e) if (v[e] > g1) { g1 = v[e]; i1 = e; }  // first-max
    float g2 = -1.f; int i2 = 0;
#pragma unroll
    for (int e = 0; e < 32; ++e) if (e != i1 && v[e] > g2) { g2 = v[e]; i2 = e; }
    const int R = blockIdx.x * 64 + tid;
    g12[R] = make_float2(g1, g2);
    idxs[R] = i1 | (i2 << 8);
#pragma unroll
    for (int e = 0; e < 32; e += 4) {  // store normalized gates back
      float4 s; s.x = v[e]; s.y = v[e + 1]; s.z = v[e + 2]; s.w = v[e + 3];
      *reinterpret_cast<float4*>(&wt[row][p * 32 + e]) = s;
    }
  }
  __syncthreads();
  if (tid < 64) {  // me partial per (p,e), tokens ascending (== k_soft order)
    const int pp = tid >> 5, ee = tid & 31;
    float s = 0.f;
    for (int tok = 0; tok < 32; ++tok) s += wt[tok][pp * 32 + ee];
    me_part[blockIdx.x * 64 + tid] = s;
  }
}

// ------- hierarchical ordered scans, 5-bit match trick -----------------------
__global__ __launch_bounds__(1024) void k_scan(const int* __restrict__ idxs,
                                               const float2* __restrict__ g12,
                                               const float* __restrict__ me_part,
                                               int2* __restrict__ fl,
                                               float2* __restrict__ wvp,
                                               float* __restrict__ out) {
  __shared__ int grp[NP][64][32];
  __shared__ int tot[NP][32];
  __shared__ unsigned short tk1[NP][T_TOK];
  __shared__ unsigned short tk2[NP][T_TOK];
  __shared__ float red[64];
  const int tid = threadIdx.x;
  const int wvi = tid >> 6;
  const int p = wvi >> 3;
  const int wg = wvi & 7;
  const int l = tid & 63;
  const unsigned long long lmask = (1ull << l) - 1ull;
  for (int gi = 0; gi < 8; ++gi) {
    const int g = wg * 8 + gi;
    const int t = g * 64 + l;
    const int e1 = idxs[t * 2 + p] & 255;
    if (l < 32) grp[p][g][l] = 0;
    unsigned long long m = ~0ull;
#pragma unroll
    for (int b = 0; b < 5; ++b) {
      const unsigned long long bm = __ballot((e1 >> b) & 1);
      m &= ((e1 >> b) & 1) ? bm : ~bm;
    }
    const int rank = (int)__popcll(m & lmask);
    if (rank == 0) grp[p][g][e1] = (int)__popcll(m);
    tk1[p][t] = (unsigned short)(rank | (e1 << 6));
  }
  __syncthreads();
  if (tid < 64) {
    const int pp = tid >> 5, ee = tid & 31;
    int s = 0;
    for (int g = 0; g < 64; ++g) { int vv = grp[pp][g][ee]; grp[pp][g][ee] = s; s += vv; }
    tot[pp][ee] = s;
  }
  __syncthreads();
  for (int gi = 0; gi < 8; ++gi) {
    const int g = wg * 8 + gi;
    const int t = g * 64 + l;
    const int vv = tk1[p][t];
    tk1[p][t] = (unsigned short)(grp[p][g][vv >> 6] + (vv & 63));
  }
  if (tid < 64) {
    float s = 0.f;
    for (int b = 0; b < 128; ++b) s += me_part[b * 64 + tid];
    red[tid] = s * (float)tot[tid >> 5][tid & 31];
  }
  __syncthreads();
  if (tid == 0) {
    float s = 0.f;
    for (int i = 0; i < 64; ++i) s += red[i];
    out[0] = s / (64.0f * 4096.0f * 4096.0f);
  }
  for (int gi = 0; gi < 8; ++gi) {
    const int g = wg * 8 + gi;
    const int t = g * 64 + l;
    const int ii = idxs[t * 2 + p];
    const int e2 = (tk1[p][t] < CAP) ? (ii >> 8) : (ii & 255);
    if (l < 32) grp[p][g][l] = 0;
    unsigned long long m = ~0ull;
#pragma unroll
    for (int b = 0; b < 5; ++b) {
      const unsigned long long bm = __ballot((e2 >> b) & 1);
      m &= ((e2 >> b) & 1) ? bm : ~bm;
    }
    const int rank = (int)__popcll(m & lmask);
    if (rank == 0) grp[p][g][e2] = (int)__popcll(m);
    tk2[p][t] = (unsigned short)(rank | (e2 << 6));
  }
  __syncthreads();
  if (tid < 64) {
    const int pp = tid >> 5, ee = tid & 31;
    int s = min(tot[pp][ee], CAP);
    for (int g = 0; g < 64; ++g) { int vv = grp[pp][g][ee]; grp[pp][g][ee] = s; s += vv; }
  }
  __syncthreads();
  for (int gi = 0; gi < 8; ++gi) {
    const int g = wg * 8 + gi;
    const int t = g * 64 + l;
    const int R = t * 2 + p;
    const int ii = idxs[R];
    const int e1 = ii & 255;
    const int loc1v = tk1[p][t];
    const bool kept1 = loc1v < CAP;
    const int v2 = tk2[p][t];
    const int rank2 = v2 & 63, e2 = v2 >> 6;
    const int loc2 = grp[p][g][e2] + rank2;
    const bool kept2 = loc2 < CAP;
    const float2 gg = g12[R];
    const float gs1 = kept1 ? gg.x : 0.f;
    const float g2v = kept1 ? gg.y : gg.x;
    const float gs2 = kept2 ? g2v : 0.f;
    const float den = fmaxf(gs1 + gs2, 1.1920929e-07f);  // FLT_EPSILON
    fl[R] = make_int2(kept1 ? e1 * CAP + loc1v : -1, kept2 ? e2 * CAP + loc2 : -1);
    wvp[R] = make_float2(gs1 / den, gs2 / den);
  }
}

// ---- point-fix: scatter the <=4 nonzeros per row into zeroed output ---------
__global__ __launch_bounds__(256) void k_fix(const int2* __restrict__ fl,
                                             const float2* __restrict__ wvp,
                                             float* __restrict__ out,
                                             int rlimit) {
  const int R = blockIdx.x * 256 + threadIdx.x;  // 0..8191
  const int2 f = fl[R];
  const float2 w = wvp[R];
  float* oc = out + 1 + (size_t)R * 5120;
  if (f.x >= 0) oc[f.x] = w.x;
  if (f.y >= 0) oc[f.y] = w.y;
  if (R < rlimit) {
    float* od = out + 1 + COMB_ELEMS + (size_t)R * 5120;
    if (f.x >= 0) od[f.x] = 1.0f;
    if (f.y >= 0) od[f.y] = 1.0f;
  }
}

// tail writer (aliasing path): zero scratch region of dispatch + its fixes
__global__ __launch_bounds__(1024) void k_write_tail(const int2* __restrict__ fl,
                                                     float* __restrict__ out,
                                                     int nfullB) {
  __shared__ int2 sfl[16];
  const int tid = threadIdx.x;
  const int rstart = nfullB * 2;
  const int nr = 8192 - rstart;      // <= 16
  if (tid < nr) sfl[tid] = fl[rstart + tid];
  __syncthreads();
  const size_t base = 1 + COMB_ELEMS + (size_t)rstart * 5120;  // == 1 mod 4
  const int cnt = nr * 5120;
  const int nx4 = (cnt - 4) >> 2;
  float4* p4 = (float4*)(out + base + 3);
  const float4 z4 = make_float4(0.f, 0.f, 0.f, 0.f);
  for (int idx = tid; idx < nx4; idx += 1024) p4[idx] = z4;
  if (tid < 3) out[base + tid] = 0.f;
  if (tid == 3) out[base + cnt - 1] = 0.f;
  __syncthreads();
  if (tid < 2 * nr) {
    const int rr = rstart + (tid >> 1);
    const int2 f = sfl[tid >> 1];
    const int pos = (tid & 1) ? f.y : f.x;
    if (pos >= 0) out[1 + COMB_ELEMS + (size_t)rr * 5120 + pos] = 1.0f;
  }
}

extern "C" void kernel_launch(void* const* d_in, const int* in_sizes, int n_in,
                              void* d_out, int out_size, void* d_ws, size_t ws_size,
                              hipStream_t stream) {
  const float* x = (const float*)d_in[0];
  const float* W = (const float*)d_in[1];
  float* out = (float*)d_out;

  float* small;
  int s2lo = 0, s2hi = 0, fillLast = 1;
  int nfullB = 4096, rlimit = 8192;
  if (ws_size >= SMALLF * sizeof(float)) {
    small = (float*)d_ws;
  } else {
    // scratch at aligned tail of d_out; fill skips it; tail kernel finishes.
    const size_t tb = (OUT_ELEMS - SMALLF) & ~(size_t)3;  // 83820544
    small = out + tb;
    s2lo = (int)(tb / 4); s2hi = TOT4;
    fillLast = 0;
    nfullB = (int)((tb - 1 - COMB_ELEMS) / 10240);        // 4089
    rlimit = nfullB * 2;
  }
  float2* g12 = (float2*)small;                 // 16384 floats
  int* idxs = (int*)(small + 16384);            //  8192
  float* me_part = small + 24576;               //  8192
  int2* fl = (int2*)(small + 32768);            // 16384
  float2* wvp = (float2*)(small + 49152);       // 16384  -> total 65536

  hipLaunchKernelGGL(k_fused, dim3(NGB + NFB), dim3(256), 0, stream,
                     x, W, g12, idxs, me_part, out, s2lo, s2hi, fillLast);
  hipLaunchKernelGGL(k_scan, dim3(1), dim3(1024), 0, stream, idxs, g12, me_part, fl, wvp, out);
  hipLaunchKernelGGL(k_fix, dim3(32), dim3(256), 0, stream, fl, wvp, out, rlimit);
  if (nfullB < 4096)
    hipLaunchKernelGGL(k_write_tail, dim3(1), dim3(1024), 0, stream, fl, out, nfullB);
}